// Round 8
// baseline (2387.823 us; speedup 1.0000x reference)
//
#include <hip/hip_runtime.h>
#include <math.h>

#define DT    0.01f
#define B_    64
#define S_    4096
#define I_    128
#define H_    256
#define O_    128

typedef _Float16 f16x8  __attribute__((ext_vector_type(8)));
typedef _Float16 half2v __attribute__((ext_vector_type(2)));
typedef float    f32x4  __attribute__((ext_vector_type(4)));

#if defined(__has_builtin)
#if __has_builtin(__builtin_amdgcn_fdot2)
#define FDOT2(a, b, c) __builtin_amdgcn_fdot2((a), (b), (c), false)
#endif
#endif
#ifndef FDOT2
#define FDOT2(a, b, c) \
  fmaf((float)(a).x, (float)(b).x, fmaf((float)(a).y, (float)(b).y, (c)))
#endif

static __device__ __forceinline__ half2v mkh2(_Float16 a, _Float16 b) {
  half2v r; r.x = a; r.y = b; return r;
}

// ---------------------------------------------------------------------------
// Kernel 1: xproj[b,t,j] = b[j] + sum_i x[b,t,i] * W[i,j]   (W rows 0..127)
// ---------------------------------------------------------------------------
#define RPB 64

__global__ __launch_bounds__(256, 2) void xproj_kernel(
    const float* __restrict__ x, const float* __restrict__ W,
    const float* __restrict__ bias, float* __restrict__ xp)
{
  __shared__ __align__(16) float xs[RPB][I_];
  const int j = threadIdx.x;

  float w[I_];
#pragma unroll
  for (int k = 0; k < I_; ++k) w[k] = W[k * H_ + j];
  const float bj = bias[j];

  const size_t row0 = (size_t)blockIdx.x * RPB;

  const float4* src4 = (const float4*)(x + row0 * I_);
  float4* xs4 = (float4*)&xs[0][0];
#pragma unroll
  for (int i = 0; i < (RPB * I_ / 4) / 256; ++i)
    xs4[j + i * 256] = src4[j + i * 256];
  __syncthreads();

  for (int r = 0; r < RPB; r += 4) {
    float a0 = bj, a1 = bj, a2 = bj, a3 = bj;
    const float4* r0 = (const float4*)xs[r + 0];
    const float4* r1 = (const float4*)xs[r + 1];
    const float4* r2 = (const float4*)xs[r + 2];
    const float4* r3 = (const float4*)xs[r + 3];
#pragma unroll
    for (int k4 = 0; k4 < I_ / 4; ++k4) {
      float4 v0 = r0[k4], v1 = r1[k4], v2 = r2[k4], v3 = r3[k4];
      a0 = fmaf(v0.x, w[4*k4+0], a0); a0 = fmaf(v0.y, w[4*k4+1], a0);
      a0 = fmaf(v0.z, w[4*k4+2], a0); a0 = fmaf(v0.w, w[4*k4+3], a0);
      a1 = fmaf(v1.x, w[4*k4+0], a1); a1 = fmaf(v1.y, w[4*k4+1], a1);
      a1 = fmaf(v1.z, w[4*k4+2], a1); a1 = fmaf(v1.w, w[4*k4+3], a1);
      a2 = fmaf(v2.x, w[4*k4+0], a2); a2 = fmaf(v2.y, w[4*k4+1], a2);
      a2 = fmaf(v2.z, w[4*k4+2], a2); a2 = fmaf(v2.w, w[4*k4+3], a2);
      a3 = fmaf(v3.x, w[4*k4+0], a3); a3 = fmaf(v3.y, w[4*k4+1], a3);
      a3 = fmaf(v3.z, w[4*k4+2], a3); a3 = fmaf(v3.w, w[4*k4+3], a3);
    }
    xp[(row0 + r + 0) * H_ + j] = a0;
    xp[(row0 + r + 1) * H_ + j] = a1;
    xp[(row0 + r + 2) * H_ + j] = a2;
    xp[(row0 + r + 3) * H_ + j] = a3;
  }
}

// ---------------------------------------------------------------------------
// Kernel 2: LTC recurrence, 512 threads = 8 waves (2/SIMD).
// Hybrid GEMV per step:
//   - MFMA computes K in [0,128): 4 K-tiles x 2 col-groups = 8 MFMA/wave
//     (16/SIMD = ~256cy matrix pipe, half of the all-MFMA mapping).
//   - VALU fdot2 computes K in [128,256) concurrently (separate pipe):
//     lane pair (l, l^16) splits the 128 terms 64/64 (gg = (l>>4)&1),
//     32 fdot2 each (f32 acc), combined via ds_swizzle xor-16.
//   - z = select(MFMA chains by l&32) + dot2 sum; C-in seeded with xpre.
// xp is staged in LDS 32 steps at a time (64KB double buffer): 4 float4
// loads issued at chunk start, LDS-written before the chunk's last barrier
// (T14 issue-early/write-late; vmcnt(0) drain cost amortized ~10cy/step).
// Per-step xpre is then a ds_read_b32. ONE __syncthreads per step.
// Fragment k-mapping (HW-verified r4-r6): lane element j covers
// k = (l>>4)*8 + j + kt*32; col = l&15; all C rows identical -> read reg 0.
// ---------------------------------------------------------------------------
__global__ __launch_bounds__(512, 2) void ltc_main(
    const float* __restrict__ xp, const float* __restrict__ W,
    const float* __restrict__ tau, const float* __restrict__ A,
    const float* __restrict__ Wo, const float* __restrict__ bo,
    float* __restrict__ out)
{
  const int b  = blockIdx.x;
  const int t  = threadIdx.x;
  const int wv = t >> 6;       // 0..7
  const int l  = t & 63;
  const int g  = l >> 4;       // k-slice group 0..3
  const int gg = g & 1;        // which 64-half of the dot2 K-chunk
  const int c  = l & 15;       // col within 16-group
  const int s  = l >> 5;       // which col-group this lane keeps
  const int o  = wv * 32 + s * 16 + c;  // this lane's output (2 lanes/output)

  // MFMA B-fragments for K in [0,128): 2 col-groups x 4 K-tiles (32 VGPR)
  f16x8 bw[2][4];
#pragma unroll
  for (int sg = 0; sg < 2; ++sg)
#pragma unroll
    for (int kt = 0; kt < 4; ++kt)
#pragma unroll
      for (int j = 0; j < 8; ++j)
        bw[sg][kt][j] =
            (_Float16)W[(I_ + kt * 32 + g * 8 + j) * H_ + (wv * 32 + sg * 16 + c)];

  // dot2 weights for K in [128,256), this lane's 64-term half (32 VGPR)
  half2v wd[32];
#pragma unroll
  for (int i = 0; i < 32; ++i) {
    const int k = I_ + 128 + gg * 64 + 2 * i;
    wd[i].x = (_Float16)W[k * H_ + o];
    wd[i].y = (_Float16)W[(k + 1) * H_ + o];
  }

  __shared__ __align__(16) _Float16 hs[2][H_];
  __shared__ float hfin[H_];
  __shared__ __align__(16) float xs[2][32][H_];  // 64KB xp chunk staging

  const float Aj   = A[o];
  const float itau = 1.0f / tau[o];
  const float dtA  = DT * Aj;
  const float base = 1.0f + DT * itau;

  const float* xpb = xp + (size_t)b * S_ * H_;

  float h = 0.0f;
  if (t < H_) hs[0][t] = (_Float16)0.0f;

  // stage chunk 0 synchronously
  {
    const float4* s4 = (const float4*)xpb;
    float4 q0 = s4[t], q1 = s4[t + 512], q2 = s4[t + 1024], q3 = s4[t + 1536];
    float4* d4 = (float4*)&xs[0][0][0];
    d4[t] = q0; d4[t + 512] = q1; d4[t + 1024] = q2; d4[t + 1536] = q3;
  }
  __syncthreads();

#define DOT8(HV, W0, W1, W2, W3)                                             \
  dv0 = FDOT2(mkh2(HV[0], HV[1]), W0, dv0);                                  \
  dv1 = FDOT2(mkh2(HV[2], HV[3]), W1, dv1);                                  \
  dv0 = FDOT2(mkh2(HV[4], HV[5]), W2, dv0);                                  \
  dv1 = FDOT2(mkh2(HV[6], HV[7]), W3, dv1);

#define LTC_BODY(RB, WB, XROW)                                               \
  {                                                                          \
    const _Float16* hb = &hs[RB][g * 8];                                     \
    f16x8 a0_ = *(const f16x8*)(hb);                                         \
    f16x8 a1_ = *(const f16x8*)(hb + 32);                                    \
    f16x8 a2_ = *(const f16x8*)(hb + 64);                                    \
    f16x8 a3_ = *(const f16x8*)(hb + 96);                                    \
    const f16x8* h2p = (const f16x8*)&hs[RB][128 + gg * 64];                 \
    f16x8 hv0 = h2p[0], hv1 = h2p[1], hv2 = h2p[2], hv3 = h2p[3];            \
    f16x8 hv4 = h2p[4], hv5 = h2p[5], hv6 = h2p[6], hv7 = h2p[7];            \
    const float xpre = (XROW)[o];                                            \
    f32x4 ac00 = {xpre, xpre, xpre, xpre};                                   \
    f32x4 ac01 = {0.f, 0.f, 0.f, 0.f};                                       \
    f32x4 ac10 = {xpre, xpre, xpre, xpre};                                   \
    f32x4 ac11 = {0.f, 0.f, 0.f, 0.f};                                       \
    ac00 = __builtin_amdgcn_mfma_f32_16x16x32_f16(a0_, bw[0][0], ac00, 0,0,0);\
    ac10 = __builtin_amdgcn_mfma_f32_16x16x32_f16(a0_, bw[1][0], ac10, 0,0,0);\
    ac01 = __builtin_amdgcn_mfma_f32_16x16x32_f16(a1_, bw[0][1], ac01, 0,0,0);\
    ac11 = __builtin_amdgcn_mfma_f32_16x16x32_f16(a1_, bw[1][1], ac11, 0,0,0);\
    ac00 = __builtin_amdgcn_mfma_f32_16x16x32_f16(a2_, bw[0][2], ac00, 0,0,0);\
    ac10 = __builtin_amdgcn_mfma_f32_16x16x32_f16(a2_, bw[1][2], ac10, 0,0,0);\
    ac01 = __builtin_amdgcn_mfma_f32_16x16x32_f16(a3_, bw[0][3], ac01, 0,0,0);\
    ac11 = __builtin_amdgcn_mfma_f32_16x16x32_f16(a3_, bw[1][3], ac11, 0,0,0);\
    float dv0 = 0.f, dv1 = 0.f;                                              \
    DOT8(hv0, wd[0],  wd[1],  wd[2],  wd[3])                                 \
    DOT8(hv1, wd[4],  wd[5],  wd[6],  wd[7])                                 \
    DOT8(hv2, wd[8],  wd[9],  wd[10], wd[11])                                \
    DOT8(hv3, wd[12], wd[13], wd[14], wd[15])                                \
    DOT8(hv4, wd[16], wd[17], wd[18], wd[19])                                \
    DOT8(hv5, wd[20], wd[21], wd[22], wd[23])                                \
    DOT8(hv6, wd[24], wd[25], wd[26], wd[27])                                \
    DOT8(hv7, wd[28], wd[29], wd[30], wd[31])                                \
    float zv = dv0 + dv1;                                                    \
    zv += __int_as_float(                                                    \
        __builtin_amdgcn_ds_swizzle(__float_as_int(zv), 0x401F));            \
    const float z0 = ac00[0] + ac01[0];                                      \
    const float z1 = ac10[0] + ac11[0];                                      \
    float z = ((l & 32) ? z1 : z0) + zv;                                     \
    z = fminf(15.0f, fmaxf(-15.0f, z));                                      \
    const float E = __expf(2.0f * z);                                        \
    const float f = (E - 1.0f) * __builtin_amdgcn_rcpf(E + 1.0f);            \
    h = fmaf(dtA, f, h) * __builtin_amdgcn_rcpf(fmaf(DT, f, base));          \
    if (!(l & 16)) hs[WB][o] = (_Float16)h;                                  \
    __syncthreads();                                                         \
  }

  const int NCH = S_ / 32;  // 128 chunks of 32 steps
  for (int ch = 0; ch < NCH; ++ch) {
    // issue next chunk's loads early (written to LDS 31 steps later)
    float4 p0, p1, p2, p3;
    const bool pf = (ch + 1 < NCH);
    if (pf) {
      const float4* s4 = (const float4*)(xpb + (size_t)(ch + 1) * 32 * H_);
      p0 = s4[t]; p1 = s4[t + 512]; p2 = s4[t + 1024]; p3 = s4[t + 1536];
    }
    const float* xc = &xs[ch & 1][0][0];
    for (int i = 0; i < 30; i += 2) {
      LTC_BODY(0, 1, xc + i * H_)
      LTC_BODY(1, 0, xc + (i + 1) * H_)
    }
    LTC_BODY(0, 1, xc + 30 * H_)
    if (pf) {
      float4* d4 = (float4*)&xs[(ch + 1) & 1][0][0];
      d4[t] = p0; d4[t + 512] = p1; d4[t + 1024] = p2; d4[t + 1536] = p3;
    }
    LTC_BODY(1, 0, xc + 31 * H_)
  }
#undef LTC_BODY
#undef DOT8

  // stage final f32 h, then fused output projection
  if (!(l & 16)) hfin[o] = h;
  __syncthreads();

  if (t < O_) {
    float accO = bo[t];
#pragma unroll 8
    for (int hh = 0; hh < H_; ++hh)
      accO = fmaf(hfin[hh], Wo[hh * O_ + t], accO);
    out[b * O_ + t] = accO;
  }
}

// ---------------------------------------------------------------------------
// Fallback (no workspace): proven structure with inline x-proj.
// ---------------------------------------------------------------------------
__global__ __launch_bounds__(1024) void ltc_inline(
    const float* __restrict__ x, const float* __restrict__ W,
    const float* __restrict__ bias, const float* __restrict__ tau,
    const float* __restrict__ A, const float* __restrict__ Wo,
    const float* __restrict__ bo, float* __restrict__ out)
{
  const int b = blockIdx.x;
  const int t = threadIdx.x;
  const int j = t & (H_ - 1);
  const int c = t >> 8;

  float wh[64], wx[32];
#pragma unroll
  for (int kk = 0; kk < 64; ++kk)
    wh[kk] = W[(I_ + c * 64 + kk) * H_ + j];
#pragma unroll
  for (int kk = 0; kk < 32; ++kk)
    wx[kk] = W[(c * 32 + kk) * H_ + j];

  __shared__ __align__(16) float hsf[H_];
  __shared__ __align__(16) float xsf[I_];
  __shared__ float ps[3][H_];

  float Aj = 0.f, itau = 0.f, bj = 0.f;
  if (c == 0) {
    Aj = A[j];
    itau = 1.0f / tau[j];
    bj = bias[j];
    hsf[j] = 0.0f;
  }
  const float4* xrow4 = (const float4*)(x + (size_t)b * S_ * I_);
  if (t < 32) ((float4*)xsf)[t] = xrow4[t];
  __syncthreads();

  for (int step = 0; step < S_; ++step) {
    float4 xnext4 = make_float4(0.f, 0.f, 0.f, 0.f);
    if (t < 32) {
      const int snext = (step + 1 < S_) ? step + 1 : step;
      xnext4 = xrow4[snext * 32 + t];
    }

    float acc = 0.0f;
#pragma unroll
    for (int kk = 0; kk < 64; kk += 4) {
      float4 h4 = *(const float4*)&hsf[c * 64 + kk];
      acc = fmaf(h4.x, wh[kk + 0], acc);
      acc = fmaf(h4.y, wh[kk + 1], acc);
      acc = fmaf(h4.z, wh[kk + 2], acc);
      acc = fmaf(h4.w, wh[kk + 3], acc);
    }
#pragma unroll
    for (int kk = 0; kk < 32; kk += 4) {
      float4 x4 = *(const float4*)&xsf[c * 32 + kk];
      acc = fmaf(x4.x, wx[kk + 0], acc);
      acc = fmaf(x4.y, wx[kk + 1], acc);
      acc = fmaf(x4.z, wx[kk + 2], acc);
      acc = fmaf(x4.w, wx[kk + 3], acc);
    }

    if (c) ps[c - 1][j] = acc;
    __syncthreads();

    if (t < 32) ((float4*)xsf)[t] = xnext4;
    if (c == 0) {
      const float z = acc + ps[0][j] + ps[1][j] + ps[2][j] + bj;
      const float f = tanhf(z);
      const float hj = hsf[j];
      hsf[j] = (hj + DT * f * Aj) / (1.0f + DT * (itau + f));
    }
    __syncthreads();
  }

  if (t < O_) {
    float acc = bo[t];
#pragma unroll 8
    for (int h = 0; h < H_; ++h)
      acc = fmaf(hsf[h], Wo[h * O_ + t], acc);
    out[b * O_ + t] = acc;
  }
}

// ---------------------------------------------------------------------------
extern "C" void kernel_launch(void* const* d_in, const int* in_sizes, int n_in,
                              void* d_out, int out_size, void* d_ws, size_t ws_size,
                              hipStream_t stream) {
  const float* x   = (const float*)d_in[0];
  const float* W   = (const float*)d_in[1];
  const float* b   = (const float*)d_in[2];
  const float* tau = (const float*)d_in[3];
  const float* A   = (const float*)d_in[4];
  const float* Wo  = (const float*)d_in[5];
  const float* bo  = (const float*)d_in[6];
  float* out = (float*)d_out;

  const size_t XP_BYTES = (size_t)B_ * S_ * H_ * sizeof(float);

  if (ws_size >= XP_BYTES) {
    float* xp = (float*)d_ws;
    hipLaunchKernelGGL(xproj_kernel, dim3((B_ * S_) / RPB), dim3(256), 0, stream,
                       x, W, b, xp);
    hipLaunchKernelGGL(ltc_main, dim3(B_), dim3(512), 0, stream,
                       xp, W, tau, A, Wo, bo, out);
  } else {
    hipLaunchKernelGGL(ltc_inline, dim3(B_), dim3(1024), 0, stream,
                       x, W, b, tau, A, Wo, bo, out);
  }
}

// Round 10
// 1859.589 us; speedup vs baseline: 1.2841x; 1.2841x over previous
//
#include <hip/hip_runtime.h>
#include <math.h>

#define DT    0.01f
#define B_    64
#define S_    4096
#define I_    128
#define H_    256
#define O_    128

typedef _Float16 f16x8 __attribute__((ext_vector_type(8)));
typedef float    f32x4 __attribute__((ext_vector_type(4)));

// ---------------------------------------------------------------------------
// Kernel 1: xproj[b,t,j] = b[j] + sum_i x[b,t,i] * W[i,j]   (W rows 0..127)
// ---------------------------------------------------------------------------
#define RPB 64

__global__ __launch_bounds__(256, 2) void xproj_kernel(
    const float* __restrict__ x, const float* __restrict__ W,
    const float* __restrict__ bias, float* __restrict__ xp)
{
  __shared__ __align__(16) float xs[RPB][I_];
  const int j = threadIdx.x;

  float w[I_];
#pragma unroll
  for (int k = 0; k < I_; ++k) w[k] = W[k * H_ + j];
  const float bj = bias[j];

  const size_t row0 = (size_t)blockIdx.x * RPB;

  const float4* src4 = (const float4*)(x + row0 * I_);
  float4* xs4 = (float4*)&xs[0][0];
#pragma unroll
  for (int i = 0; i < (RPB * I_ / 4) / 256; ++i)
    xs4[j + i * 256] = src4[j + i * 256];
  __syncthreads();

  for (int r = 0; r < RPB; r += 4) {
    float a0 = bj, a1 = bj, a2 = bj, a3 = bj;
    const float4* r0 = (const float4*)xs[r + 0];
    const float4* r1 = (const float4*)xs[r + 1];
    const float4* r2 = (const float4*)xs[r + 2];
    const float4* r3 = (const float4*)xs[r + 3];
#pragma unroll
    for (int k4 = 0; k4 < I_ / 4; ++k4) {
      float4 v0 = r0[k4], v1 = r1[k4], v2 = r2[k4], v3 = r3[k4];
      a0 = fmaf(v0.x, w[4*k4+0], a0); a0 = fmaf(v0.y, w[4*k4+1], a0);
      a0 = fmaf(v0.z, w[4*k4+2], a0); a0 = fmaf(v0.w, w[4*k4+3], a0);
      a1 = fmaf(v1.x, w[4*k4+0], a1); a1 = fmaf(v1.y, w[4*k4+1], a1);
      a1 = fmaf(v1.z, w[4*k4+2], a1); a1 = fmaf(v1.w, w[4*k4+3], a1);
      a2 = fmaf(v2.x, w[4*k4+0], a2); a2 = fmaf(v2.y, w[4*k4+1], a2);
      a2 = fmaf(v2.z, w[4*k4+2], a2); a2 = fmaf(v2.w, w[4*k4+3], a2);
      a3 = fmaf(v3.x, w[4*k4+0], a3); a3 = fmaf(v3.y, w[4*k4+1], a3);
      a3 = fmaf(v3.z, w[4*k4+2], a3); a3 = fmaf(v3.w, w[4*k4+3], a3);
    }
    xp[(row0 + r + 0) * H_ + j] = a0;
    xp[(row0 + r + 1) * H_ + j] = a1;
    xp[(row0 + r + 2) * H_ + j] = a2;
    xp[(row0 + r + 3) * H_ + j] = a3;
  }
}

// ---------------------------------------------------------------------------
// Kernel 2: LTC recurrence via MFMA, 1024 threads = 16 waves (4/SIMD).
// Same passing r6 structure, scaled: wave wv owns 16 outputs [wv*16,wv*16+16)
// via ONE B-fragment set; 8 MFMA/wave as 2 independent 4-deep chains ->
// 8 chains/SIMD (2x r6's ILP; r6 PMC showed 16cy/MFMA effective vs ~9.7
// throughput => dependency-limited, more chains should compress the window).
// Lane l: k-group g=l>>4, col c=l&15, output o=wv*16+c (4 lanes/output,
// redundant update is cheap: shortened algebra below). C-in chain0 seeded
// with xpre (uniform per column since o is g-independent).
// Update algebra (symbolically exact): with E=exp(2z),
//   h' = (E*p + q)/(E*rc + sc), p=h+dtA, q=h-dtA (computed off critical
//   path at previous step's end), rc=base+DT, sc=base-DT.
// Lanes 0..15 write h' (f16) to the other hs buffer; ONE __syncthreads.
// Fragment mapping as r4-r6 (consistency-verified): element j of lane l is
// k = g*8+j within the tile; any C reg works (all A rows identical), reg 0.
// ---------------------------------------------------------------------------
__global__ __launch_bounds__(1024, 4) void ltc_main(
    const float* __restrict__ xp, const float* __restrict__ W,
    const float* __restrict__ tau, const float* __restrict__ A,
    const float* __restrict__ Wo, const float* __restrict__ bo,
    float* __restrict__ out)
{
  const int b  = blockIdx.x;
  const int t  = threadIdx.x;
  const int wv = t >> 6;       // 0..15
  const int l  = t & 63;
  const int g  = l >> 4;       // k-slice group 0..3
  const int c  = l & 15;       // col within 16-group
  const int o  = wv * 16 + c;  // this lane's output (4 lanes/output)

  // B-fragments: 8 K-tiles, register-resident (32 VGPR)
  f16x8 bw[8];
#pragma unroll
  for (int kt = 0; kt < 8; ++kt)
#pragma unroll
    for (int j = 0; j < 8; ++j)
      bw[kt][j] = (_Float16)W[(I_ + kt * 32 + g * 8 + j) * H_ + o];

  __shared__ __align__(16) _Float16 hs[2][H_];
  __shared__ float hfin[H_];

  const float dtA  = DT * A[o];
  const float base = 1.0f + DT * (1.0f / tau[o]);
  const float rc   = base + DT;
  const float sc   = base - DT;

  const float* xprow = xp + (size_t)b * S_ * H_ + o;

  float h = 0.0f, p = dtA, q = -dtA;
  float xpre = xprow[0];
  if (t < H_) hs[0][t] = (_Float16)0.0f;
  __syncthreads();

#define LTC_BODY(RB, WB, STEP)                                               \
  {                                                                          \
    const _Float16* hb = &hs[RB][g * 8];                                     \
    const int snext = ((STEP) + 1 < S_) ? (STEP) + 1 : (STEP);               \
    const float xnext = xprow[(size_t)snext * H_];                           \
    f16x8 a0_ = *(const f16x8*)(hb);                                         \
    f16x8 a1_ = *(const f16x8*)(hb + 32);                                    \
    f16x8 a2_ = *(const f16x8*)(hb + 64);                                    \
    f16x8 a3_ = *(const f16x8*)(hb + 96);                                    \
    f16x8 a4_ = *(const f16x8*)(hb + 128);                                   \
    f16x8 a5_ = *(const f16x8*)(hb + 160);                                   \
    f16x8 a6_ = *(const f16x8*)(hb + 192);                                   \
    f16x8 a7_ = *(const f16x8*)(hb + 224);                                   \
    f32x4 ac0 = {xpre, xpre, xpre, xpre};                                    \
    f32x4 ac1 = {0.f, 0.f, 0.f, 0.f};                                        \
    __builtin_amdgcn_s_setprio(1);                                           \
    ac0 = __builtin_amdgcn_mfma_f32_16x16x32_f16(a0_, bw[0], ac0, 0, 0, 0);  \
    ac1 = __builtin_amdgcn_mfma_f32_16x16x32_f16(a4_, bw[4], ac1, 0, 0, 0);  \
    ac0 = __builtin_amdgcn_mfma_f32_16x16x32_f16(a1_, bw[1], ac0, 0, 0, 0);  \
    ac1 = __builtin_amdgcn_mfma_f32_16x16x32_f16(a5_, bw[5], ac1, 0, 0, 0);  \
    ac0 = __builtin_amdgcn_mfma_f32_16x16x32_f16(a2_, bw[2], ac0, 0, 0, 0);  \
    ac1 = __builtin_amdgcn_mfma_f32_16x16x32_f16(a6_, bw[6], ac1, 0, 0, 0);  \
    ac0 = __builtin_amdgcn_mfma_f32_16x16x32_f16(a3_, bw[3], ac0, 0, 0, 0);  \
    ac1 = __builtin_amdgcn_mfma_f32_16x16x32_f16(a7_, bw[7], ac1, 0, 0, 0);  \
    __builtin_amdgcn_s_setprio(0);                                           \
    float z = ac0[0] + ac1[0];                                               \
    z = fminf(15.0f, fmaxf(-15.0f, z));                                      \
    const float E = __expf(2.0f * z);                                        \
    const float den = fmaf(E, rc, sc);                                       \
    const float num = fmaf(E, p, q);                                         \
    h = num * __builtin_amdgcn_rcpf(den);                                    \
    p = h + dtA;                                                             \
    q = h - dtA;                                                             \
    if (l < 16) hs[WB][o] = (_Float16)h;                                     \
    xpre = xnext;                                                            \
    __syncthreads();                                                         \
  }

  for (int st = 0; st < S_; st += 2) {
    LTC_BODY(0, 1, st)
    LTC_BODY(1, 0, st + 1)
  }
#undef LTC_BODY

  // stage final f32 h, then fused output projection
  if (l < 16) hfin[o] = h;
  __syncthreads();

  if (t < O_) {
    float accO = bo[t];
#pragma unroll 8
    for (int hh = 0; hh < H_; ++hh)
      accO = fmaf(hfin[hh], Wo[hh * O_ + t], accO);
    out[b * O_ + t] = accO;
  }
}

// ---------------------------------------------------------------------------
// Fallback (no workspace): proven structure with inline x-proj.
// ---------------------------------------------------------------------------
__global__ __launch_bounds__(1024) void ltc_inline(
    const float* __restrict__ x, const float* __restrict__ W,
    const float* __restrict__ bias, const float* __restrict__ tau,
    const float* __restrict__ A, const float* __restrict__ Wo,
    const float* __restrict__ bo, float* __restrict__ out)
{
  const int b = blockIdx.x;
  const int t = threadIdx.x;
  const int j = t & (H_ - 1);
  const int c = t >> 8;

  float wh[64], wx[32];
#pragma unroll
  for (int kk = 0; kk < 64; ++kk)
    wh[kk] = W[(I_ + c * 64 + kk) * H_ + j];
#pragma unroll
  for (int kk = 0; kk < 32; ++kk)
    wx[kk] = W[(c * 32 + kk) * H_ + j];

  __shared__ __align__(16) float hsf[H_];
  __shared__ __align__(16) float xsf[I_];
  __shared__ float ps[3][H_];

  float Aj = 0.f, itau = 0.f, bj = 0.f;
  if (c == 0) {
    Aj = A[j];
    itau = 1.0f / tau[j];
    bj = bias[j];
    hsf[j] = 0.0f;
  }
  const float4* xrow4 = (const float4*)(x + (size_t)b * S_ * I_);
  if (t < 32) ((float4*)xsf)[t] = xrow4[t];
  __syncthreads();

  for (int step = 0; step < S_; ++step) {
    float4 xnext4 = make_float4(0.f, 0.f, 0.f, 0.f);
    if (t < 32) {
      const int snext = (step + 1 < S_) ? step + 1 : step;
      xnext4 = xrow4[snext * 32 + t];
    }

    float acc = 0.0f;
#pragma unroll
    for (int kk = 0; kk < 64; kk += 4) {
      float4 h4 = *(const float4*)&hsf[c * 64 + kk];
      acc = fmaf(h4.x, wh[kk + 0], acc);
      acc = fmaf(h4.y, wh[kk + 1], acc);
      acc = fmaf(h4.z, wh[kk + 2], acc);
      acc = fmaf(h4.w, wh[kk + 3], acc);
    }
#pragma unroll
    for (int kk = 0; kk < 32; kk += 4) {
      float4 x4 = *(const float4*)&xsf[c * 32 + kk];
      acc = fmaf(x4.x, wx[kk + 0], acc);
      acc = fmaf(x4.y, wx[kk + 1], acc);
      acc = fmaf(x4.z, wx[kk + 2], acc);
      acc = fmaf(x4.w, wx[kk + 3], acc);
    }

    if (c) ps[c - 1][j] = acc;
    __syncthreads();

    if (t < 32) ((float4*)xsf)[t] = xnext4;
    if (c == 0) {
      const float z = acc + ps[0][j] + ps[1][j] + ps[2][j] + bj;
      const float f = tanhf(z);
      const float hj = hsf[j];
      hsf[j] = (hj + DT * f * Aj) / (1.0f + DT * (itau + f));
    }
    __syncthreads();
  }

  if (t < O_) {
    float acc = bo[t];
#pragma unroll 8
    for (int h = 0; h < H_; ++h)
      acc = fmaf(hsf[h], Wo[h * O_ + t], acc);
    out[b * O_ + t] = acc;
  }
}

// ---------------------------------------------------------------------------
extern "C" void kernel_launch(void* const* d_in, const int* in_sizes, int n_in,
                              void* d_out, int out_size, void* d_ws, size_t ws_size,
                              hipStream_t stream) {
  const float* x   = (const float*)d_in[0];
  const float* W   = (const float*)d_in[1];
  const float* b   = (const float*)d_in[2];
  const float* tau = (const float*)d_in[3];
  const float* A   = (const float*)d_in[4];
  const float* Wo  = (const float*)d_in[5];
  const float* bo  = (const float*)d_in[6];
  float* out = (float*)d_out;

  const size_t XP_BYTES = (size_t)B_ * S_ * H_ * sizeof(float);

  if (ws_size >= XP_BYTES) {
    float* xp = (float*)d_ws;
    hipLaunchKernelGGL(xproj_kernel, dim3((B_ * S_) / RPB), dim3(256), 0, stream,
                       x, W, b, xp);
    hipLaunchKernelGGL(ltc_main, dim3(B_), dim3(1024), 0, stream,
                       xp, W, tau, A, Wo, bo, out);
  } else {
    hipLaunchKernelGGL(ltc_inline, dim3(B_), dim3(1024), 0, stream,
                       x, W, b, tau, A, Wo, bo, out);
  }
}